// Round 17
// baseline (146.056 us; speedup 1.0000x reference)
//
#include <hip/hip_runtime.h>
#include <hip/hip_bf16.h>

// ---------------------------------------------------------------------------
// CosineGraphAttentionLayer: O = softmax(beta*cos(xi,xj) + mask(adj)) @ xj
// N=M=8192, D=256, f32 in/out.
//
// R17 = R15 (validated 128.4us) + dual-sacc QK chain made register-feasible:
// adj loads issued AFTER QK (av's 16 regs dead across the QK peak -> dual
// chains fit under the 256-VGPR cliff) and top-wait is vmcnt(0) (spill-
// immune, R12-validated; adj is ~0.6 iter old at the drain so cost ~0).
// Prep kernels separate (R16's fusion reverted). Everything else byte-R15.
// ---------------------------------------------------------------------------

typedef _Float16 half8  __attribute__((ext_vector_type(8)));
typedef _Float16 half4v __attribute__((ext_vector_type(4)));
typedef __fp16   fp16x2 __attribute__((ext_vector_type(2)));
typedef float    f32x16 __attribute__((ext_vector_type(16)));
typedef int      i32x4  __attribute__((ext_vector_type(4)));
typedef unsigned long long u64;

#define GAS __attribute__((address_space(1)))
#define LAS __attribute__((address_space(3)))

#define N_ROWS 8192
#define M_ROWS 8192
#define DDIM   256

// ---- prep: xi * beta/||xi|| -> f16 (validated) -----------------------------
__global__ void prep_scale(const float* __restrict__ x, _Float16* __restrict__ xs,
                           const float* __restrict__ betap) {
    int row  = blockIdx.x * 4 + (threadIdx.x >> 6);
    int lane = threadIdx.x & 63;
    const float4 v = *(const float4*)(x + (size_t)row * DDIM + lane * 4);
    float ss = v.x * v.x + v.y * v.y + v.z * v.z + v.w * v.w;
#pragma unroll
    for (int o = 32; o > 0; o >>= 1) ss += __shfl_xor(ss, o, 64);
    float sc = betap[0] / sqrtf(ss);
    half4v hv = {(_Float16)(v.x * sc), (_Float16)(v.y * sc),
                 (_Float16)(v.z * sc), (_Float16)(v.w * sc)};
    *(half4v*)(xs + (size_t)row * DDIM + lane * 4) = hv;
}

// ---- prep: xj -> frag-major xjA (normalized) / xjF (raw) (validated) -------
__global__ void prep_xj(const float* __restrict__ xj, half8* __restrict__ xjA,
                        half8* __restrict__ xjF) {
    __shared__ _Float16 tileR[32][272];
    __shared__ _Float16 tileN[32][272];
    __shared__ float red[32][8];
    __shared__ float rsc[32];
    const int t  = threadIdx.x;
    const int jb = blockIdx.x;
    const int row = t >> 3, seg = t & 7;
    const float* src = xj + (size_t)(jb * 32 + row) * DDIM + seg * 32;
    float4 v[8];
    float ss = 0.f;
#pragma unroll
    for (int q = 0; q < 8; ++q) {
        v[q] = ((const float4*)src)[q];
        ss += v[q].x * v[q].x + v[q].y * v[q].y + v[q].z * v[q].z + v[q].w * v[q].w;
    }
    red[row][seg] = ss;
    __syncthreads();
    if (t < 32) {
        float s = 0.f;
#pragma unroll
        for (int q = 0; q < 8; ++q) s += red[t][q];
        rsc[t] = 1.0f / sqrtf(s);
    }
    __syncthreads();
    const float sc = rsc[row];
#pragma unroll
    for (int q = 0; q < 8; ++q) {
        int c = seg * 32 + q * 4;
        tileR[row][c + 0] = (_Float16)v[q].x;
        tileR[row][c + 1] = (_Float16)v[q].y;
        tileR[row][c + 2] = (_Float16)v[q].z;
        tileR[row][c + 3] = (_Float16)v[q].w;
        tileN[row][c + 0] = (_Float16)(v[q].x * sc);
        tileN[row][c + 1] = (_Float16)(v[q].y * sc);
        tileN[row][c + 2] = (_Float16)(v[q].z * sc);
        tileN[row][c + 3] = (_Float16)(v[q].w * sc);
    }
    __syncthreads();
#pragma unroll
    for (int rep = 0; rep < 4; ++rep) {
        int idx = t + rep * 256;
        int kt = idx >> 6, l = idx & 63, il = l & 31, hh = l >> 5;
        half8 val = *(const half8*)&tileN[il][kt * 16 + hh * 8];
        xjA[((size_t)jb * 16 + kt) * 64 + l] = val;
    }
#pragma unroll
    for (int rep = 0; rep < 4; ++rep) {
        int idx = t + rep * 256;
        int f = idx >> 7, s = (idx >> 6) & 1, l = idx & 63, il = l & 31, hh = l >> 5;
        int d = f * 32 + il, jl = s * 16 + hh * 8;
        half8 val;
#pragma unroll
        for (int e = 0; e < 8; ++e) val[e] = tileR[jl + e][d];
        xjF[((size_t)jb * 16 + f * 2 + s) * 64 + l] = val;
    }
}

// ---- main fused kernel -----------------------------------------------------
// 512 blocks x 256 threads (4 waves; 2 blocks/CU). jsplit = bid&7 (1024-j
// eighth), itile = bid>>3 (128-i tile). Wave w: i-subtile w (32 i), 256 d.
// 32 iters of 32-j tiles; A(16K)+F(16K) double-buffered via global_load_lds.
// Per iter: vmcnt(0)+s_barrier (spill-immune), STAGE(t+1), ballot(av from
// t-1), cw-read, dual-chain QK, adj-issue (post-QK: av dead across QK),
// exp/pack, PV. Mask in per-wave LDS slot ring. f16x2 partial epilogue.
__global__ __launch_bounds__(256, 2)
void attn_main(const _Float16* __restrict__ xi_s, const half8* __restrict__ xjA,
               const half8* __restrict__ xjF, const int* __restrict__ adj,
               unsigned* __restrict__ part, float* __restrict__ denp) {
    extern __shared__ char lds[];
    const int tid  = threadIdx.x;
    const int w    = tid >> 6;
    const int lane = tid & 63;
    const int il   = lane & 31;
    const int h    = lane >> 5;

    const int bid    = blockIdx.x;
    const int jsplit = bid & 7;
    const int itile  = bid >> 3;
    const int ibase  = itile * 128;
    const int irow   = ibase + w * 32 + il;
    const int j0blk  = jsplit * 32;          // first 32-j block of our eighth
    const int mbase  = 65536 + w * 3072;     // per-wave mask region (3 slots)

    f32x16 acc[8];
#pragma unroll
    for (int f = 0; f < 8; ++f)
#pragma unroll
        for (int r = 0; r < 16; ++r) acc[f][r] = 0.f;
    float rden = 0.f;

    const char* gA = (const char*)xjA;
    const char* gF = (const char*)xjF;
    // per-lane adj base: row (ibase+w*32+?), this jsplit's 1024-j window
    const int* arow0 = adj + (size_t)(ibase + w * 32) * M_ROWS + jsplit * 1024 + 4 * lane;

    // pack one adj row's 256-j window into 4 u64 words in LDS slot
#define PACKROW(SLOT, R, V)                                                     \
    {                                                                           \
        u64 b0 = __ballot((V)[0] != 0);                                         \
        u64 b1 = __ballot((V)[1] != 0);                                         \
        u64 b2 = __ballot((V)[2] != 0);                                         \
        u64 b3 = __ballot((V)[3] != 0);                                         \
        if (lane == (R)) {                                                      \
            char* mp = lds + mbase + (SLOT) * 1024 + (R) * 32;                  \
            *(u64*)(mp)      = b0; *(u64*)(mp + 8)  = b1;                       \
            *(u64*)(mp + 16) = b2; *(u64*)(mp + 24) = b3;                       \
        }                                                                       \
    }

    // STAGE tile T (32KB: A 16K | F 16K) into buffer B; waves 0,1 stage A,
    // waves 2,3 stage F; 8 x 1KB global_load_lds per wave, linear dest.
#define STAGE(T, B)                                                             \
    {                                                                           \
        const size_t blk = (size_t)(j0blk + (T)) * 16384;                       \
        const char* src = (w < 2 ? gA : gF) + blk + (w & 1) * 8192 + (lane << 4); \
        char* dst = lds + (B) * 32768 + (w < 2 ? 0 : 16384) + (w & 1) * 8192 + (lane << 4); \
        _Pragma("unroll")                                                       \
        for (int k = 0; k < 8; ++k)                                             \
            __builtin_amdgcn_global_load_lds(                                   \
                (const GAS unsigned int*)(src + k * 1024),                      \
                (LAS unsigned int*)(dst + k * 1024), 16, 0, 0);                 \
    }

    // ---- prologue: pack group 0 -> slot 0 (4 batches of 8 rows) ----
    for (int b = 0; b < 4; ++b) {
        i32x4 av8[8];
#pragma unroll
        for (int rr = 0; rr < 8; ++rr)
            av8[rr] = __builtin_nontemporal_load(
                (const i32x4*)(arow0 + (size_t)(b * 8 + rr) * M_ROWS));
#pragma unroll
        for (int rr = 0; rr < 8; ++rr) PACKROW(0, b * 8 + rr, av8[rr]);
    }

    // xi B-operand frags
    half8 bq[16];
#pragma unroll
    for (int kt = 0; kt < 16; ++kt)
        bq[kt] = *(const half8*)(xi_s + (size_t)irow * DDIM + kt * 16 + h * 8);

    STAGE(0, 0);
    u64 cw0 = 0, cw1 = 0, cw2 = 0, cw3 = 0;
    i32x4 av[4];

    for (int t = 0; t < 32; ++t) {
        // drain ALL outstanding VMEM (stage t + adj issued mid-iter t-1 —
        // both comfortably landed; over-drain is spill-immune), then sync.
        asm volatile("s_waitcnt vmcnt(0)" ::: "memory");
        __builtin_amdgcn_s_barrier();
        __builtin_amdgcn_sched_barrier(0);

        // stage next tile into the buffer last read at iter t-1
        if (t < 31) STAGE(t + 1, (t + 1) & 1);

        // ballots for adj rows loaded at iter t-1 (already landed)
        if (t >= 1 && t <= 24) {
            const int gp   = ((t - 1) >> 3) + 1;
            const int slot = gp % 3;
            const int r0p  = 4 * ((t - 1) & 7);
#pragma unroll
            for (int rr = 0; rr < 4; ++rr) PACKROW(slot, r0p + rr, av[rr]);
        }
        // group start: load this group's mask words from our LDS slot
        if ((t & 7) == 0) {
            const char* mp = lds + mbase + ((t >> 3) % 3) * 1024 + il * 32;
            cw0 = *(const u64*)(mp);      cw1 = *(const u64*)(mp + 8);
            cw2 = *(const u64*)(mp + 16); cw3 = *(const u64*)(mp + 24);
        }

        const char* bufA = lds + (t & 1) * 32768;
        const char* bufF = bufA + 16384;

        // QK^T: S^T[j][i], 32j x 32i — two interleaved chains for MFMA ILP
        // (av is DEAD here: issued below, consumed at next iter's ballot)
        f32x16 sacc0, sacc1;
#pragma unroll
        for (int r = 0; r < 16; ++r) { sacc0[r] = 0.f; sacc1[r] = 0.f; }
        __builtin_amdgcn_s_setprio(1);
#pragma unroll
        for (int kt = 0; kt < 16; kt += 2) {
            half8 a0 = *(const half8*)(bufA + kt * 1024 + (lane << 4));
            sacc0 = __builtin_amdgcn_mfma_f32_32x32x16_f16(a0, bq[kt], sacc0, 0, 0, 0);
            half8 a1 = *(const half8*)(bufA + (kt + 1) * 1024 + (lane << 4));
            sacc1 = __builtin_amdgcn_mfma_f32_32x32x16_f16(a1, bq[kt + 1], sacc1, 0, 0, 0);
        }
        __builtin_amdgcn_s_setprio(0);

        // issue adj rows for group (t>>3)+1 (balloted next iter; ~0.6-iter
        // slack before the top-of-iter drain)
        if (t < 24) {
            const int gg = (t >> 3) + 1;
            const int r0 = 4 * (t & 7);
            const int* ap = arow0 + gg * 256;
#pragma unroll
            for (int rr = 0; rr < 4; ++rr)
                av[rr] = __builtin_nontemporal_load(
                    (const i32x4*)(ap + (size_t)(r0 + rr) * M_ROWS));
        }

        // masked exp folded into pack (|s|<1, no max tracking)
        const unsigned s0 = 8 * (t & 7) + h;
        const unsigned x0 = (unsigned)(cw0 >> s0), x1 = (unsigned)(cw1 >> s0);
        const unsigned x2 = (unsigned)(cw2 >> s0), x3 = (unsigned)(cw3 >> s0);
        int pq[8], qq[8];
#pragma unroll
        for (int q = 0; q < 8; ++q) {
            const int r0_ = 2 * q, r1_ = 2 * q + 1;
            unsigned xa = ((r0_ & 3) == 0) ? x0 : ((r0_ & 3) == 1) ? x1 : ((r0_ & 3) == 2) ? x2 : x3;
            unsigned xb = ((r1_ & 3) == 0) ? x0 : ((r1_ & 3) == 1) ? x1 : ((r1_ & 3) == 2) ? x2 : x3;
            float e0 = ((xa >> (2 * (r0_ >> 2))) & 1u) ? __expf(sacc0[r0_] + sacc1[r0_]) : 0.f;
            float e1 = ((xb >> (2 * (r1_ >> 2))) & 1u) ? __expf(sacc0[r1_] + sacc1[r1_]) : 0.f;
            rden += e0 + e1;
            fp16x2 pp = __builtin_amdgcn_cvt_pkrtz(e0, e1);
            pq[q] = __builtin_bit_cast(int, pp);
            qq[q] = __shfl_xor(pq[q], 32, 64);
        }
        i32x4 af0 = {h ? qq[2] : pq[0], h ? qq[3] : pq[1], h ? pq[2] : qq[0], h ? pq[3] : qq[1]};
        i32x4 af1 = {h ? qq[6] : pq[4], h ? qq[7] : pq[5], h ? pq[6] : qq[4], h ? pq[7] : qq[5]};
        half8 afA = __builtin_bit_cast(half8, af0);
        half8 afB = __builtin_bit_cast(half8, af1);

        // PV: O[i][d] += W[i][j] * V[j][d], k = 32 j, all 256 d
        __builtin_amdgcn_s_setprio(1);
#pragma unroll
        for (int f = 0; f < 8; ++f) {
            half8 b0 = *(const half8*)(bufF + (f * 2 + 0) * 1024 + (lane << 4));
            acc[f] = __builtin_amdgcn_mfma_f32_32x32x16_f16(afA, b0, acc[f], 0, 0, 0);
            half8 b1 = *(const half8*)(bufF + (f * 2 + 1) * 1024 + (lane << 4));
            acc[f] = __builtin_amdgcn_mfma_f32_32x32x16_f16(afB, b1, acc[f], 0, 0, 0);
        }
        __builtin_amdgcn_s_setprio(0);
    }

    // den partial: plain store
    rden += __shfl_xor(rden, 32, 64);
    if (lane < 32) denp[(size_t)jsplit * N_ROWS + ibase + w * 32 + lane] = rden;

    // output partial: f16x2-packed plain stores (word g*32+il holds
    // d = 64g+il (lo) and d = 64g+32+il (hi))
    unsigned* prow = part + (size_t)jsplit * ((size_t)N_ROWS * 128);
#pragma unroll
    for (int g = 0; g < 4; ++g) {
#pragma unroll
        for (int r = 0; r < 16; ++r) {
            int ir = (r & 3) + 8 * (r >> 2) + 4 * h;
            fp16x2 pk = __builtin_amdgcn_cvt_pkrtz(acc[2 * g][r], acc[2 * g + 1][r]);
            prow[(size_t)(ibase + w * 32 + ir) * 128 + g * 32 + il] =
                __builtin_bit_cast(unsigned, pk);
        }
    }
#undef STAGE
#undef PACKROW
}

// ---- reduce: out[i][d] = sum_s unpack(part[s][i]) / sum_s denp[s][i] -------
__global__ void reduce_out(const unsigned* __restrict__ part, const float* __restrict__ denp,
                           float* __restrict__ out) {
    const int row = blockIdx.x;
    const int wi  = threadIdx.x;          // 0..127 packed-word index
    float slo = 0.f, shi = 0.f;
#pragma unroll
    for (int q = 0; q < 8; ++q) {
        unsigned u = part[((size_t)q * N_ROWS + row) * 128 + wi];
        fp16x2 hx = __builtin_bit_cast(fp16x2, u);
        slo += (float)hx[0];
        shi += (float)hx[1];
    }
    float dn = 0.f;
#pragma unroll
    for (int q = 0; q < 8; ++q)
        dn += denp[(size_t)q * N_ROWS + row];
    const int dlo = 64 * (wi >> 5) + (wi & 31);
    out[(size_t)row * DDIM + dlo]      = slo / dn;
    out[(size_t)row * DDIM + dlo + 32] = shi / dn;
}

extern "C" void kernel_launch(void* const* d_in, const int* in_sizes, int n_in,
                              void* d_out, int out_size, void* d_ws, size_t ws_size,
                              hipStream_t stream) {
    const float* xi   = (const float*)d_in[0];
    const float* xj   = (const float*)d_in[1];
    const int*   adj  = (const int*)d_in[2];
    const float* beta = (const float*)d_in[3];
    float* out = (float*)d_out;
    char*  ws  = (char*)d_ws;

    _Float16* xi_s  = (_Float16*)(ws);                // 4MB
    half8*    xjA   = (half8*)(ws + (4u << 20));      // 4MB
    half8*    xjF   = (half8*)(ws + (8u << 20));      // 4MB
    float*    denp  = (float*)(ws + (12u << 20));     // 8 x 32KB = 256KB
    unsigned* part  = (unsigned*)(ws + (16u << 20));  // 8 x 4MB = 32MB

    hipFuncSetAttribute((const void*)attn_main,
                        hipFuncAttributeMaxDynamicSharedMemorySize, 77824);

    prep_scale<<<N_ROWS / 4, 256, 0, stream>>>(xi, xi_s, beta);
    prep_xj<<<M_ROWS / 32, 256, 0, stream>>>(xj, xjA, xjF);
    attn_main<<<512, 256, 77824, stream>>>(xi_s, xjA, xjF, adj, part, denp);
    reduce_out<<<N_ROWS, 128, 0, stream>>>(part, denp, out);
}

// Round 18
// 127.188 us; speedup vs baseline: 1.1483x; 1.1483x over previous
//
#include <hip/hip_runtime.h>
#include <hip/hip_bf16.h>

// ---------------------------------------------------------------------------
// CosineGraphAttentionLayer: O = softmax(beta*cos(xi,xj) + mask(adj)) @ xj
// N=M=8192, D=256, f32 in/out.
//
// R18 = byte-exact revert to R15 (validated 128.4us — best so far).
// R16/R17 established: dual-sacc QK regresses (+9.5/+17.7us); the single-
// chain schedule with counted per-wave vmcnt(4) adj slack, setprio MFMA
// clusters, and f16x2-packed partial outputs is the empirical optimum of
// this structure.
// ---------------------------------------------------------------------------

typedef _Float16 half8  __attribute__((ext_vector_type(8)));
typedef _Float16 half4v __attribute__((ext_vector_type(4)));
typedef __fp16   fp16x2 __attribute__((ext_vector_type(2)));
typedef float    f32x16 __attribute__((ext_vector_type(16)));
typedef int      i32x4  __attribute__((ext_vector_type(4)));
typedef unsigned long long u64;

#define GAS __attribute__((address_space(1)))
#define LAS __attribute__((address_space(3)))

#define N_ROWS 8192
#define M_ROWS 8192
#define DDIM   256

// ---- prep: xi * beta/||xi|| -> f16 (validated) -----------------------------
__global__ void prep_scale(const float* __restrict__ x, _Float16* __restrict__ xs,
                           const float* __restrict__ betap) {
    int row  = blockIdx.x * 4 + (threadIdx.x >> 6);
    int lane = threadIdx.x & 63;
    const float4 v = *(const float4*)(x + (size_t)row * DDIM + lane * 4);
    float ss = v.x * v.x + v.y * v.y + v.z * v.z + v.w * v.w;
#pragma unroll
    for (int o = 32; o > 0; o >>= 1) ss += __shfl_xor(ss, o, 64);
    float sc = betap[0] / sqrtf(ss);
    half4v hv = {(_Float16)(v.x * sc), (_Float16)(v.y * sc),
                 (_Float16)(v.z * sc), (_Float16)(v.w * sc)};
    *(half4v*)(xs + (size_t)row * DDIM + lane * 4) = hv;
}

// ---- prep: xj -> frag-major xjA (normalized) / xjF (raw) (validated) -------
__global__ void prep_xj(const float* __restrict__ xj, half8* __restrict__ xjA,
                        half8* __restrict__ xjF) {
    __shared__ _Float16 tileR[32][272];
    __shared__ _Float16 tileN[32][272];
    __shared__ float red[32][8];
    __shared__ float rsc[32];
    const int t  = threadIdx.x;
    const int jb = blockIdx.x;
    const int row = t >> 3, seg = t & 7;
    const float* src = xj + (size_t)(jb * 32 + row) * DDIM + seg * 32;
    float4 v[8];
    float ss = 0.f;
#pragma unroll
    for (int q = 0; q < 8; ++q) {
        v[q] = ((const float4*)src)[q];
        ss += v[q].x * v[q].x + v[q].y * v[q].y + v[q].z * v[q].z + v[q].w * v[q].w;
    }
    red[row][seg] = ss;
    __syncthreads();
    if (t < 32) {
        float s = 0.f;
#pragma unroll
        for (int q = 0; q < 8; ++q) s += red[t][q];
        rsc[t] = 1.0f / sqrtf(s);
    }
    __syncthreads();
    const float sc = rsc[row];
#pragma unroll
    for (int q = 0; q < 8; ++q) {
        int c = seg * 32 + q * 4;
        tileR[row][c + 0] = (_Float16)v[q].x;
        tileR[row][c + 1] = (_Float16)v[q].y;
        tileR[row][c + 2] = (_Float16)v[q].z;
        tileR[row][c + 3] = (_Float16)v[q].w;
        tileN[row][c + 0] = (_Float16)(v[q].x * sc);
        tileN[row][c + 1] = (_Float16)(v[q].y * sc);
        tileN[row][c + 2] = (_Float16)(v[q].z * sc);
        tileN[row][c + 3] = (_Float16)(v[q].w * sc);
    }
    __syncthreads();
#pragma unroll
    for (int rep = 0; rep < 4; ++rep) {
        int idx = t + rep * 256;
        int kt = idx >> 6, l = idx & 63, il = l & 31, hh = l >> 5;
        half8 val = *(const half8*)&tileN[il][kt * 16 + hh * 8];
        xjA[((size_t)jb * 16 + kt) * 64 + l] = val;
    }
#pragma unroll
    for (int rep = 0; rep < 4; ++rep) {
        int idx = t + rep * 256;
        int f = idx >> 7, s = (idx >> 6) & 1, l = idx & 63, il = l & 31, hh = l >> 5;
        int d = f * 32 + il, jl = s * 16 + hh * 8;
        half8 val;
#pragma unroll
        for (int e = 0; e < 8; ++e) val[e] = tileR[jl + e][d];
        xjF[((size_t)jb * 16 + f * 2 + s) * 64 + l] = val;
    }
}

// ---- main fused kernel -----------------------------------------------------
// 512 blocks x 256 threads (4 waves; 2 blocks/CU). jsplit = bid&7 (1024-j
// eighth), itile = bid>>3 (128-i tile). Wave w: i-subtile w (32 i), 256 d.
// 32 iters of 32-j tiles; A(16K)+F(16K) double-buffered via global_load_lds.
// Counted top-wait vmcnt(4) keeps adj loads flying across the barrier.
// Mask: ballot-packed into per-wave LDS slot ring. LDS: 64K dbuf + 12K mask.
// Epilogue: f16x2-packed partial stores (no atomics).
__global__ __launch_bounds__(256, 2)
void attn_main(const _Float16* __restrict__ xi_s, const half8* __restrict__ xjA,
               const half8* __restrict__ xjF, const int* __restrict__ adj,
               unsigned* __restrict__ part, float* __restrict__ denp) {
    extern __shared__ char lds[];
    const int tid  = threadIdx.x;
    const int w    = tid >> 6;
    const int lane = tid & 63;
    const int il   = lane & 31;
    const int h    = lane >> 5;

    const int bid    = blockIdx.x;
    const int jsplit = bid & 7;
    const int itile  = bid >> 3;
    const int ibase  = itile * 128;
    const int irow   = ibase + w * 32 + il;
    const int j0blk  = jsplit * 32;          // first 32-j block of our eighth
    const int mbase  = 65536 + w * 3072;     // per-wave mask region (3 slots)

    f32x16 acc[8];
#pragma unroll
    for (int f = 0; f < 8; ++f)
#pragma unroll
        for (int r = 0; r < 16; ++r) acc[f][r] = 0.f;
    float rden = 0.f;

    const char* gA = (const char*)xjA;
    const char* gF = (const char*)xjF;
    // per-lane adj base: row (ibase+w*32+?), this jsplit's 1024-j window
    const int* arow0 = adj + (size_t)(ibase + w * 32) * M_ROWS + jsplit * 1024 + 4 * lane;

    // pack one adj row's 256-j window into 4 u64 words in LDS slot
#define PACKROW(SLOT, R, V)                                                     \
    {                                                                           \
        u64 b0 = __ballot((V)[0] != 0);                                         \
        u64 b1 = __ballot((V)[1] != 0);                                         \
        u64 b2 = __ballot((V)[2] != 0);                                         \
        u64 b3 = __ballot((V)[3] != 0);                                         \
        if (lane == (R)) {                                                      \
            char* mp = lds + mbase + (SLOT) * 1024 + (R) * 32;                  \
            *(u64*)(mp)      = b0; *(u64*)(mp + 8)  = b1;                       \
            *(u64*)(mp + 16) = b2; *(u64*)(mp + 24) = b3;                       \
        }                                                                       \
    }

    // STAGE tile T (32KB: A 16K | F 16K) into buffer B; waves 0,1 stage A,
    // waves 2,3 stage F; 8 x 1KB global_load_lds per wave, linear dest.
#define STAGE(T, B)                                                             \
    {                                                                           \
        const size_t blk = (size_t)(j0blk + (T)) * 16384;                       \
        const char* src = (w < 2 ? gA : gF) + blk + (w & 1) * 8192 + (lane << 4); \
        char* dst = lds + (B) * 32768 + (w < 2 ? 0 : 16384) + (w & 1) * 8192 + (lane << 4); \
        _Pragma("unroll")                                                       \
        for (int k = 0; k < 8; ++k)                                             \
            __builtin_amdgcn_global_load_lds(                                   \
                (const GAS unsigned int*)(src + k * 1024),                      \
                (LAS unsigned int*)(dst + k * 1024), 16, 0, 0);                 \
    }

    // ---- prologue: pack group 0 -> slot 0 (4 batches of 8 rows) ----
    for (int b = 0; b < 4; ++b) {
        i32x4 av8[8];
#pragma unroll
        for (int rr = 0; rr < 8; ++rr)
            av8[rr] = __builtin_nontemporal_load(
                (const i32x4*)(arow0 + (size_t)(b * 8 + rr) * M_ROWS));
#pragma unroll
        for (int rr = 0; rr < 8; ++rr) PACKROW(0, b * 8 + rr, av8[rr]);
    }

    // xi B-operand frags
    half8 bq[16];
#pragma unroll
    for (int kt = 0; kt < 16; ++kt)
        bq[kt] = *(const half8*)(xi_s + (size_t)irow * DDIM + kt * 16 + h * 8);

    STAGE(0, 0);
    u64 cw0 = 0, cw1 = 0, cw2 = 0, cw3 = 0;
    i32x4 av[4];

    for (int t = 0; t < 32; ++t) {
        // counted top-wait: stage(t) = the 8 oldest VMEM ops of this wave;
        // adj(t-1) (4 youngest, in flight iff 1<=t<=24) keeps flying.
        if (t >= 1 && t <= 24) {
            asm volatile("s_waitcnt vmcnt(4)" ::: "memory");
        } else {
            asm volatile("s_waitcnt vmcnt(0)" ::: "memory");
        }
        __builtin_amdgcn_s_barrier();
        __builtin_amdgcn_sched_barrier(0);

        // stage next tile into the buffer last read at iter t-1
        if (t < 31) STAGE(t + 1, (t + 1) & 1);

        // ballots for adj rows loaded at iter t-1 (compiler emits a COUNTED
        // wait: the 8 stage(t+1) loads just issued stay in flight)
        if (t >= 1 && t <= 24) {
            const int gp   = ((t - 1) >> 3) + 1;
            const int slot = gp % 3;
            const int r0p  = 4 * ((t - 1) & 7);
#pragma unroll
            for (int rr = 0; rr < 4; ++rr) PACKROW(slot, r0p + rr, av[rr]);
        }
        // issue adj rows for group (t>>3)+1 (balloted next iter)
        if (t < 24) {
            const int gg = (t >> 3) + 1;
            const int r0 = 4 * (t & 7);
            const int* ap = arow0 + gg * 256;
#pragma unroll
            for (int rr = 0; rr < 4; ++rr)
                av[rr] = __builtin_nontemporal_load(
                    (const i32x4*)(ap + (size_t)(r0 + rr) * M_ROWS));
        }
        // group start: load this group's mask words from our LDS slot
        if ((t & 7) == 0) {
            const char* mp = lds + mbase + ((t >> 3) % 3) * 1024 + il * 32;
            cw0 = *(const u64*)(mp);      cw1 = *(const u64*)(mp + 8);
            cw2 = *(const u64*)(mp + 16); cw3 = *(const u64*)(mp + 24);
        }

        const char* bufA = lds + (t & 1) * 32768;
        const char* bufF = bufA + 16384;

        // QK^T: S^T[j][i], 32j x 32i
        f32x16 sacc;
#pragma unroll
        for (int r = 0; r < 16; ++r) sacc[r] = 0.f;
        __builtin_amdgcn_s_setprio(1);
#pragma unroll
        for (int kt = 0; kt < 16; ++kt) {
            half8 a0 = *(const half8*)(bufA + kt * 1024 + (lane << 4));
            sacc = __builtin_amdgcn_mfma_f32_32x32x16_f16(a0, bq[kt], sacc, 0, 0, 0);
        }
        __builtin_amdgcn_s_setprio(0);
        // masked exp folded into pack (|s|<1, no max tracking)
        const unsigned s0 = 8 * (t & 7) + h;
        const unsigned x0 = (unsigned)(cw0 >> s0), x1 = (unsigned)(cw1 >> s0);
        const unsigned x2 = (unsigned)(cw2 >> s0), x3 = (unsigned)(cw3 >> s0);
        int pq[8], qq[8];
#pragma unroll
        for (int q = 0; q < 8; ++q) {
            const int r0_ = 2 * q, r1_ = 2 * q + 1;
            unsigned xa = ((r0_ & 3) == 0) ? x0 : ((r0_ & 3) == 1) ? x1 : ((r0_ & 3) == 2) ? x2 : x3;
            unsigned xb = ((r1_ & 3) == 0) ? x0 : ((r1_ & 3) == 1) ? x1 : ((r1_ & 3) == 2) ? x2 : x3;
            float e0 = ((xa >> (2 * (r0_ >> 2))) & 1u) ? __expf(sacc[r0_]) : 0.f;
            float e1 = ((xb >> (2 * (r1_ >> 2))) & 1u) ? __expf(sacc[r1_]) : 0.f;
            rden += e0 + e1;
            fp16x2 pp = __builtin_amdgcn_cvt_pkrtz(e0, e1);
            pq[q] = __builtin_bit_cast(int, pp);
            qq[q] = __shfl_xor(pq[q], 32, 64);
        }
        i32x4 af0 = {h ? qq[2] : pq[0], h ? qq[3] : pq[1], h ? pq[2] : qq[0], h ? pq[3] : qq[1]};
        i32x4 af1 = {h ? qq[6] : pq[4], h ? qq[7] : pq[5], h ? pq[6] : qq[4], h ? pq[7] : qq[5]};
        half8 afA = __builtin_bit_cast(half8, af0);
        half8 afB = __builtin_bit_cast(half8, af1);

        // PV: O[i][d] += W[i][j] * V[j][d], k = 32 j, all 256 d
        __builtin_amdgcn_s_setprio(1);
#pragma unroll
        for (int f = 0; f < 8; ++f) {
            half8 b0 = *(const half8*)(bufF + (f * 2 + 0) * 1024 + (lane << 4));
            acc[f] = __builtin_amdgcn_mfma_f32_32x32x16_f16(afA, b0, acc[f], 0, 0, 0);
            half8 b1 = *(const half8*)(bufF + (f * 2 + 1) * 1024 + (lane << 4));
            acc[f] = __builtin_amdgcn_mfma_f32_32x32x16_f16(afB, b1, acc[f], 0, 0, 0);
        }
        __builtin_amdgcn_s_setprio(0);
    }

    // den partial: plain store
    rden += __shfl_xor(rden, 32, 64);
    if (lane < 32) denp[(size_t)jsplit * N_ROWS + ibase + w * 32 + lane] = rden;

    // output partial: f16x2-packed plain stores (word g*32+il holds
    // d = 64g+il (lo) and d = 64g+32+il (hi))
    unsigned* prow = part + (size_t)jsplit * ((size_t)N_ROWS * 128);
#pragma unroll
    for (int g = 0; g < 4; ++g) {
#pragma unroll
        for (int r = 0; r < 16; ++r) {
            int ir = (r & 3) + 8 * (r >> 2) + 4 * h;
            fp16x2 pk = __builtin_amdgcn_cvt_pkrtz(acc[2 * g][r], acc[2 * g + 1][r]);
            prow[(size_t)(ibase + w * 32 + ir) * 128 + g * 32 + il] =
                __builtin_bit_cast(unsigned, pk);
        }
    }
#undef STAGE
#undef PACKROW
}

// ---- reduce: out[i][d] = sum_s unpack(part[s][i]) / sum_s denp[s][i] -------
__global__ void reduce_out(const unsigned* __restrict__ part, const float* __restrict__ denp,
                           float* __restrict__ out) {
    const int row = blockIdx.x;
    const int wi  = threadIdx.x;          // 0..127 packed-word index
    float slo = 0.f, shi = 0.f;
#pragma unroll
    for (int q = 0; q < 8; ++q) {
        unsigned u = part[((size_t)q * N_ROWS + row) * 128 + wi];
        fp16x2 hx = __builtin_bit_cast(fp16x2, u);
        slo += (float)hx[0];
        shi += (float)hx[1];
    }
    float dn = 0.f;
#pragma unroll
    for (int q = 0; q < 8; ++q)
        dn += denp[(size_t)q * N_ROWS + row];
    const int dlo = 64 * (wi >> 5) + (wi & 31);
    out[(size_t)row * DDIM + dlo]      = slo / dn;
    out[(size_t)row * DDIM + dlo + 32] = shi / dn;
}

extern "C" void kernel_launch(void* const* d_in, const int* in_sizes, int n_in,
                              void* d_out, int out_size, void* d_ws, size_t ws_size,
                              hipStream_t stream) {
    const float* xi   = (const float*)d_in[0];
    const float* xj   = (const float*)d_in[1];
    const int*   adj  = (const int*)d_in[2];
    const float* beta = (const float*)d_in[3];
    float* out = (float*)d_out;
    char*  ws  = (char*)d_ws;

    _Float16* xi_s  = (_Float16*)(ws);                // 4MB
    half8*    xjA   = (half8*)(ws + (4u << 20));      // 4MB
    half8*    xjF   = (half8*)(ws + (8u << 20));      // 4MB
    float*    denp  = (float*)(ws + (12u << 20));     // 8 x 32KB = 256KB
    unsigned* part  = (unsigned*)(ws + (16u << 20));  // 8 x 4MB = 32MB

    hipFuncSetAttribute((const void*)attn_main,
                        hipFuncAttributeMaxDynamicSharedMemorySize, 77824);

    prep_scale<<<N_ROWS / 4, 256, 0, stream>>>(xi, xi_s, beta);
    prep_xj<<<M_ROWS / 32, 256, 0, stream>>>(xj, xjA, xjF);
    attn_main<<<512, 256, 77824, stream>>>(xi_s, xjA, xjF, adj, part, denp);
    reduce_out<<<N_ROWS, 128, 0, stream>>>(part, denp, out);
}